// Round 1
// baseline (863.801 us; speedup 1.0000x reference)
//
#include <hip/hip_runtime.h>
#include <hip/hip_bf16.h>

#define B_ 32
#define N_ 2048
#define D_ 16
#define J_ 64
#define C_ 32
#define NCHUNK 16
#define ICHUNK 128   // N_/NCHUNK

typedef __attribute__((ext_vector_type(8)))  short short8;
typedef __attribute__((ext_vector_type(4)))  short s16x4;
typedef __attribute__((ext_vector_type(16))) float f32x16;
typedef __attribute__((ext_vector_type(4)))  float f32x4;

using bf16_t = __hip_bfloat16;

// ---------------------------------------------------------------------------
// Prep: u (B,N,D) fp32 -> u_t (N,B,D) bf16, write-coalesced.
// A-frag for mfma_32x32x16: lane holds A[m=lane&31][k=(lane>>5)*8 + e], so
// (i, b, d)-contiguous layout gives one 16B load/lane covering the tile.
// ---------------------------------------------------------------------------
__global__ __launch_bounds__(256) void prep_u_kernel(const float* __restrict__ x,
                                                     bf16_t* __restrict__ ut) {
  int t  = blockIdx.x * 256 + threadIdx.x;   // t = (i*32 + b)*4 + d4
  int d4 = t & 3;
  int bi = t >> 2;
  int b  = bi & 31;
  int i  = bi >> 5;
  f32x4 xv = *(const f32x4*)(x + ((size_t)(b * N_ + i) * D_ + d4 * 4));
  union { s16x4 v; bf16_t h[4]; } o;
  o.h[0] = __float2bfloat16(xv.x);
  o.h[1] = __float2bfloat16(xv.y);
  o.h[2] = __float2bfloat16(xv.z);
  o.h[3] = __float2bfloat16(xv.w);
  *(s16x4*)(ut + (size_t)(i * B_ + b) * D_ + d4 * 4) = o.v;
}

// ---------------------------------------------------------------------------
// Routing pass. One block = (j, i-chunk of 128), 4 waves, 1 wave = 32 i's.
// Per (i,j): one v_mfma_f32_32x32x16_bf16 gives u_hat[b=0..31, c=0..31].
// MODE 0: fp32 W in, store bf16 W, uniform weights (iter 0, big ws)
// MODE 1: bf16 W in, V-based logits (iters 1-4, big ws)
// MODE 2: fp32 W in, uniform, no store (iter 0, small ws fallback)
// MODE 3: fp32 W in, V-based logits, no store (fallback)
// ---------------------------------------------------------------------------
template<int MODE>
__global__ __launch_bounds__(256) void pass_kernel(
    const float*  __restrict__ Wf,
    const bf16_t* __restrict__ Wb,
    bf16_t*       __restrict__ Wbo,
    const bf16_t* __restrict__ ut,
    const float*  __restrict__ V,
    float*        __restrict__ PS,
    float*        __restrict__ PZ)
{
  constexpr bool UNIFORM = (MODE == 0 || MODE == 2);
  constexpr bool READF32 = (MODE != 1);
  constexpr bool STOREB  = (MODE == 0);

  const int tid  = threadIdx.x;
  const int w    = tid >> 6;
  const int lane = tid & 63;
  const int half = lane >> 5;
  const int lc   = lane & 31;          // = c (C/D col, B-frag n); = b for A-frag m

  const int j  = blockIdx.x / NCHUNK;
  const int ch = blockIdx.x % NCHUNK;

  // C/D layout (measured, m74/m101): row b = (r&3) + 8*(r>>2) + 4*half
  int brow[16];
#pragma unroll
  for (int r = 0; r < 16; ++r) brow[r] = (r & 3) + 4 * half + 8 * (r >> 2);

  float Vreg[16];
  if (!UNIFORM) {
#pragma unroll
    for (int r = 0; r < 16; ++r) Vreg[r] = V[(brow[r] * J_ + j) * C_ + lc];
  }

  float S[16];
  float z[16];
#pragma unroll
  for (int r = 0; r < 16; ++r) { S[r] = 0.f; z[r] = 0.f; }

  const int ibase = ch * ICHUNK + w * 32;
  const int frag_off = lc * D_ + half * 8;   // lane offset inside a 32x16 tile

  const f32x16 zeroacc = {0,0,0,0,0,0,0,0,0,0,0,0,0,0,0,0};

  for (int t = 0; t < 32; ++t) {
    const int i = ibase + t;
    short8 afrag = *(const short8*)(ut + (size_t)i * (B_ * D_) + frag_off);
    short8 bfrag;
    const size_t tile = ((size_t)i * J_ + j) * (C_ * D_);
    if (READF32) {
      const float* wp = Wf + tile + frag_off;
      f32x4 w0 = *(const f32x4*)(wp);
      f32x4 w1 = *(const f32x4*)(wp + 4);
      union { short8 v; bf16_t h[8]; } cv;
      cv.h[0] = __float2bfloat16(w0.x);
      cv.h[1] = __float2bfloat16(w0.y);
      cv.h[2] = __float2bfloat16(w0.z);
      cv.h[3] = __float2bfloat16(w0.w);
      cv.h[4] = __float2bfloat16(w1.x);
      cv.h[5] = __float2bfloat16(w1.y);
      cv.h[6] = __float2bfloat16(w1.z);
      cv.h[7] = __float2bfloat16(w1.w);
      bfrag = cv.v;
      if (STOREB) *(short8*)(Wbo + tile + frag_off) = bfrag;
    } else {
      bfrag = *(const short8*)(Wb + tile + frag_off);
    }

    f32x16 acc = __builtin_amdgcn_mfma_f32_32x32x16_bf16(afrag, bfrag, zeroacc, 0, 0, 0);

    if (UNIFORM) {
#pragma unroll
      for (int r = 0; r < 16; ++r) S[r] += acc[r];
    } else {
#pragma unroll
      for (int r = 0; r < 16; ++r) {
        float p = Vreg[r] * acc[r];          // V[b,c] * u_hat[b,c]
        p += __shfl_xor(p, 1);               // reduce over c (lanes within half)
        p += __shfl_xor(p, 2);
        p += __shfl_xor(p, 4);
        p += __shfl_xor(p, 8);
        p += __shfl_xor(p, 16);
        float e = __expf(p);                 // logits are O(0.5); max-free safe
        z[r] += e;
        S[r] = fmaf(e, acc[r], S[r]);
      }
    }
  }

  // Combine 4 waves -> per-block partial (b=32, c=32) + Z(b=32)
  __shared__ float S_lds[4 * 1024];
  __shared__ float Z_lds[4 * 32];
#pragma unroll
  for (int r = 0; r < 16; ++r)
    S_lds[w * 1024 + brow[r] * 32 + lc] = S[r];
  if (lc == 0) {
#pragma unroll
    for (int r = 0; r < 16; ++r)
      Z_lds[w * 32 + brow[r]] = UNIFORM ? 32.0f : z[r];
  }
  __syncthreads();

  const size_t pbase = (size_t)blockIdx.x * 1024;
  for (int e = tid; e < 1024; e += 256)
    PS[pbase + e] = S_lds[e] + S_lds[1024 + e] + S_lds[2048 + e] + S_lds[3072 + e];
  if (tid < 32)
    PZ[(size_t)blockIdx.x * 32 + tid] =
        Z_lds[tid] + Z_lds[32 + tid] + Z_lds[64 + tid] + Z_lds[96 + tid];
}

// ---------------------------------------------------------------------------
// Combine chunks -> s, squash -> v, V += v, final iter writes output.
// 32 lanes = one (b,j) row (c across lanes).
// ---------------------------------------------------------------------------
__global__ __launch_bounds__(256) void combine_kernel(
    const float* __restrict__ PS, const float* __restrict__ PZ,
    float* __restrict__ V, float* __restrict__ out, int first, int last)
{
  int t  = blockIdx.x * 256 + threadIdx.x;  // ((b*J + j)*32 + c)
  int c  = t & 31;
  int bj = t >> 5;
  int b  = bj >> 6;
  int j  = bj & 63;
  float s = 0.f, zz = 0.f;
#pragma unroll
  for (int ch = 0; ch < NCHUNK; ++ch) {
    s  += PS[(size_t)(j * NCHUNK + ch) * 1024 + b * 32 + c];
    zz += PZ[(j * NCHUNK + ch) * 32 + b];
  }
  float sv = s / zz + 1e-7f;                // squash adds eps per-component
  float n = sv * sv;
  n += __shfl_xor(n, 1);
  n += __shfl_xor(n, 2);
  n += __shfl_xor(n, 4);
  n += __shfl_xor(n, 8);
  n += __shfl_xor(n, 16);
  float f = n / ((1.f + n) * sqrtf(n));
  float v = sv * f;
  float Vn = first ? v : (V[t] + v);
  V[t] = Vn;
  if (last) out[t] = v;
}

extern "C" void kernel_launch(void* const* d_in, const int* in_sizes, int n_in,
                              void* d_out, int out_size, void* d_ws, size_t ws_size,
                              hipStream_t stream)
{
  const float* x  = (const float*)d_in[0];
  const float* Wf = (const float*)d_in[1];
  float* out = (float*)d_out;
  char* ws = (char*)d_ws;

  const size_t SZ_WB = (size_t)N_ * J_ * C_ * D_ * 2;      // 128 MB bf16 W cache
  const size_t SZ_UT = (size_t)N_ * B_ * D_ * 2;           // 2 MB
  const size_t SZ_V  = (size_t)B_ * J_ * C_ * 4;           // 256 KB
  const size_t SZ_PS = (size_t)J_ * NCHUNK * B_ * C_ * 4;  // 4 MB
  const size_t SZ_PZ = (size_t)J_ * NCHUNK * B_ * 4;       // 128 KB

  const bool big = ws_size >= SZ_WB + SZ_UT + SZ_V + SZ_PS + SZ_PZ;
  size_t off = big ? SZ_WB : 0;
  bf16_t* Wb = (bf16_t*)ws;
  bf16_t* ut = (bf16_t*)(ws + off); off += SZ_UT;
  float*  V  = (float*)(ws + off);  off += SZ_V;
  float*  PS = (float*)(ws + off);  off += SZ_PS;
  float*  PZ = (float*)(ws + off);

  prep_u_kernel<<<dim3((N_ * B_ * 4) / 256), dim3(256), 0, stream>>>(x, ut);

  dim3 gA(J_ * NCHUNK), blk(256), gB((B_ * J_ * C_) / 256);
  if (big) {
    pass_kernel<0><<<gA, blk, 0, stream>>>(Wf, nullptr, Wb, ut, nullptr, PS, PZ);
    combine_kernel<<<gB, blk, 0, stream>>>(PS, PZ, V, out, 1, 0);
    for (int it = 1; it < 5; ++it) {
      pass_kernel<1><<<gA, blk, 0, stream>>>(nullptr, Wb, nullptr, ut, V, PS, PZ);
      combine_kernel<<<gB, blk, 0, stream>>>(PS, PZ, V, out, 0, it == 4 ? 1 : 0);
    }
  } else {
    pass_kernel<2><<<gA, blk, 0, stream>>>(Wf, nullptr, nullptr, ut, nullptr, PS, PZ);
    combine_kernel<<<gB, blk, 0, stream>>>(PS, PZ, V, out, 1, 0);
    for (int it = 1; it < 5; ++it) {
      pass_kernel<3><<<gA, blk, 0, stream>>>(Wf, nullptr, nullptr, ut, V, PS, PZ);
      combine_kernel<<<gB, blk, 0, stream>>>(PS, PZ, V, out, 0, it == 4 ? 1 : 0);
    }
  }
}

// Round 2
// 510.616 us; speedup vs baseline: 1.6917x; 1.6917x over previous
//
#include <hip/hip_runtime.h>
#include <hip/hip_bf16.h>

#define B_ 32
#define N_ 2048
#define D_ 16
#define J_ 64
#define C_ 32
#define NCHUNK 32
#define ICHUNK 64          // N_/NCHUNK
#define IPW    16          // ICHUNK/4 waves

typedef __attribute__((ext_vector_type(8)))  short short8;
typedef __attribute__((ext_vector_type(4)))  short s16x4;
typedef __attribute__((ext_vector_type(16))) float f32x16;
typedef __attribute__((ext_vector_type(4)))  float f32x4;

using bf16_t = __hip_bfloat16;

// ---------------------------------------------------------------------------
// Prep: u (B,N,D) fp32 -> u_t (N,B,D) bf16, write-coalesced.
// ---------------------------------------------------------------------------
__global__ __launch_bounds__(256) void prep_u_kernel(const float* __restrict__ x,
                                                     bf16_t* __restrict__ ut) {
  int t  = blockIdx.x * 256 + threadIdx.x;   // t = (i*32 + b)*4 + d4
  int d4 = t & 3;
  int bi = t >> 2;
  int b  = bi & 31;
  int i  = bi >> 5;
  f32x4 xv = *(const f32x4*)(x + ((size_t)(b * N_ + i) * D_ + d4 * 4));
  union { s16x4 v; bf16_t h[4]; } o;
  o.h[0] = __float2bfloat16(xv.x);
  o.h[1] = __float2bfloat16(xv.y);
  o.h[2] = __float2bfloat16(xv.z);
  o.h[3] = __float2bfloat16(xv.w);
  *(s16x4*)(ut + (size_t)(i * B_ + b) * D_ + d4 * 4) = o.v;
}

// ---------------------------------------------------------------------------
// Routing pass. One block = (j, i-chunk of 64), 4 waves, 1 wave = 16 i's.
// SWAPPED OPERANDS: mfma(wfrag, ufrag) -> acc[m=c][n=b]:
//   col b = lane&31, row c = (r&3) + 4*(lane>>5) + 8*(r>>2)
// So the logit dot over c is IN-LANE (16 fma) + one shfl_xor(32); exp is
// 1/lane/i. A and B frags have identical lane->(free,k) layouts, so the
// loads are byte-identical to the round-1 kernel (verified end-to-end).
// MODE 0: fp32 W in, store bf16 W, uniform weights (iter 0, big ws)
// MODE 1: bf16 W in, V-based logits (iters 1-4, big ws)
// MODE 2: fp32 W in, uniform, no store (fallback iter 0)
// MODE 3: fp32 W in, V-based logits, no store (fallback)
// ---------------------------------------------------------------------------
template<int MODE>
__global__ __launch_bounds__(256) void pass_kernel(
    const float*  __restrict__ Wf,
    const bf16_t* __restrict__ Wb,
    bf16_t*       __restrict__ Wbo,
    const bf16_t* __restrict__ ut,
    const float*  __restrict__ V,
    float*        __restrict__ PS,
    float*        __restrict__ PZ)
{
  constexpr bool UNIFORM = (MODE == 0 || MODE == 2);
  constexpr bool READF32 = (MODE != 1);
  constexpr bool STOREB  = (MODE == 0);

  const int tid  = threadIdx.x;
  const int w    = tid >> 6;
  const int lane = tid & 63;
  const int half = lane >> 5;
  const int lc   = lane & 31;          // = b (D col) ; also A-frag m / B-frag n

  const int j  = blockIdx.x / NCHUNK;
  const int ch = blockIdx.x % NCHUNK;

  // C/D row (= c) per accumulator reg (measured m74/m101)
  int crow[16];
#pragma unroll
  for (int r = 0; r < 16; ++r) crow[r] = (r & 3) + 4 * half + 8 * (r >> 2);

  float Vreg[16];
  if (!UNIFORM) {
#pragma unroll
    for (int r = 0; r < 16; ++r) Vreg[r] = V[(lc * J_ + j) * C_ + crow[r]];
  }

  float S[16];
#pragma unroll
  for (int r = 0; r < 16; ++r) S[r] = 0.f;
  float zacc = 0.f;

  const int ibase = ch * ICHUNK + w * IPW;
  const int frag_off = lc * D_ + half * 8;   // lane offset inside a 32x16 tile

  const f32x16 zeroacc = {0,0,0,0,0,0,0,0,0,0,0,0,0,0,0,0};

  for (int t = 0; t < IPW; ++t) {
    const int i = ibase + t;
    short8 ufrag = *(const short8*)(ut + (size_t)i * (B_ * D_) + frag_off);
    short8 wfrag;
    const size_t tile = ((size_t)i * J_ + j) * (C_ * D_);
    if (READF32) {
      const float* wp = Wf + tile + frag_off;
      f32x4 w0 = *(const f32x4*)(wp);
      f32x4 w1 = *(const f32x4*)(wp + 4);
      union { short8 v; bf16_t h[8]; } cv;
      cv.h[0] = __float2bfloat16(w0.x);
      cv.h[1] = __float2bfloat16(w0.y);
      cv.h[2] = __float2bfloat16(w0.z);
      cv.h[3] = __float2bfloat16(w0.w);
      cv.h[4] = __float2bfloat16(w1.x);
      cv.h[5] = __float2bfloat16(w1.y);
      cv.h[6] = __float2bfloat16(w1.z);
      cv.h[7] = __float2bfloat16(w1.w);
      wfrag = cv.v;
      if (STOREB) *(short8*)(Wbo + tile + frag_off) = wfrag;
    } else {
      wfrag = *(const short8*)(Wb + tile + frag_off);
    }

    // acc[m=c][n=b]
    f32x16 acc = __builtin_amdgcn_mfma_f32_32x32x16_bf16(wfrag, ufrag, zeroacc, 0, 0, 0);

    if (UNIFORM) {
#pragma unroll
      for (int r = 0; r < 16; ++r) S[r] += acc[r];
    } else {
      float ph = 0.f;
#pragma unroll
      for (int r = 0; r < 16; ++r) ph = fmaf(Vreg[r], acc[r], ph);
      ph += __shfl_xor(ph, 32);            // combine the two half-row sets
      float e = __expf(ph);                // logits are O(0.5); max-free safe
      zacc += e;
#pragma unroll
      for (int r = 0; r < 16; ++r) S[r] = fmaf(e, acc[r], S[r]);
    }
  }

  // Epilogue: transpose [c][b] -> [b][c] through padded LDS (stride 33:
  // bank = (lc + crow) % 32, conflict-free), then coalesced PS writes.
  __shared__ float S_lds[4 * 32 * 33];
  __shared__ float Z_lds[4 * 32];
#pragma unroll
  for (int r = 0; r < 16; ++r)
    S_lds[w * 1056 + lc * 33 + crow[r]] = S[r];
  if (!half)
    Z_lds[w * 32 + lc] = UNIFORM ? (float)IPW : zacc;
  __syncthreads();

  const size_t pbase = (size_t)blockIdx.x * 1024;
  for (int e = tid; e < 1024; e += 256) {
    int b = e >> 5, c = e & 31;
    PS[pbase + e] = S_lds[b * 33 + c] + S_lds[1056 + b * 33 + c] +
                    S_lds[2112 + b * 33 + c] + S_lds[3168 + b * 33 + c];
  }
  if (tid < 32)
    PZ[(size_t)blockIdx.x * 32 + tid] =
        Z_lds[tid] + Z_lds[32 + tid] + Z_lds[64 + tid] + Z_lds[96 + tid];
}

// ---------------------------------------------------------------------------
// Combine chunks -> s, squash -> v, V += v, final iter writes output.
// ---------------------------------------------------------------------------
__global__ __launch_bounds__(256) void combine_kernel(
    const float* __restrict__ PS, const float* __restrict__ PZ,
    float* __restrict__ V, float* __restrict__ out, int first, int last)
{
  int t  = blockIdx.x * 256 + threadIdx.x;  // ((b*J + j)*32 + c)
  int c  = t & 31;
  int bj = t >> 5;
  int b  = bj >> 6;
  int j  = bj & 63;
  float s = 0.f, zz = 0.f;
#pragma unroll
  for (int ch = 0; ch < NCHUNK; ++ch) {
    s  += PS[(size_t)(j * NCHUNK + ch) * 1024 + b * 32 + c];
    zz += PZ[(j * NCHUNK + ch) * 32 + b];
  }
  float sv = s / zz + 1e-7f;                // squash adds eps per-component
  float n = sv * sv;
  n += __shfl_xor(n, 1);
  n += __shfl_xor(n, 2);
  n += __shfl_xor(n, 4);
  n += __shfl_xor(n, 8);
  n += __shfl_xor(n, 16);
  float f = n / ((1.f + n) * sqrtf(n));
  float v = sv * f;
  float Vn = first ? v : (V[t] + v);
  V[t] = Vn;
  if (last) out[t] = v;
}

extern "C" void kernel_launch(void* const* d_in, const int* in_sizes, int n_in,
                              void* d_out, int out_size, void* d_ws, size_t ws_size,
                              hipStream_t stream)
{
  const float* x  = (const float*)d_in[0];
  const float* Wf = (const float*)d_in[1];
  float* out = (float*)d_out;
  char* ws = (char*)d_ws;

  const size_t SZ_WB = (size_t)N_ * J_ * C_ * D_ * 2;      // 128 MB bf16 W cache
  const size_t SZ_UT = (size_t)N_ * B_ * D_ * 2;           // 2 MB
  const size_t SZ_V  = (size_t)B_ * J_ * C_ * 4;           // 256 KB
  const size_t SZ_PS = (size_t)J_ * NCHUNK * B_ * C_ * 4;  // 8 MB
  const size_t SZ_PZ = (size_t)J_ * NCHUNK * B_ * 4;       // 256 KB

  const bool big = ws_size >= SZ_WB + SZ_UT + SZ_V + SZ_PS + SZ_PZ;
  size_t off = big ? SZ_WB : 0;
  bf16_t* Wb = (bf16_t*)ws;
  bf16_t* ut = (bf16_t*)(ws + off); off += SZ_UT;
  float*  V  = (float*)(ws + off);  off += SZ_V;
  float*  PS = (float*)(ws + off);  off += SZ_PS;
  float*  PZ = (float*)(ws + off);

  prep_u_kernel<<<dim3((N_ * B_ * 4) / 256), dim3(256), 0, stream>>>(x, ut);

  dim3 gA(J_ * NCHUNK), blk(256), gB((B_ * J_ * C_) / 256);
  if (big) {
    pass_kernel<0><<<gA, blk, 0, stream>>>(Wf, nullptr, Wb, ut, nullptr, PS, PZ);
    combine_kernel<<<gB, blk, 0, stream>>>(PS, PZ, V, out, 1, 0);
    for (int it = 1; it < 5; ++it) {
      pass_kernel<1><<<gA, blk, 0, stream>>>(nullptr, Wb, nullptr, ut, V, PS, PZ);
      combine_kernel<<<gB, blk, 0, stream>>>(PS, PZ, V, out, 0, it == 4 ? 1 : 0);
    }
  } else {
    pass_kernel<2><<<gA, blk, 0, stream>>>(Wf, nullptr, nullptr, ut, nullptr, PS, PZ);
    combine_kernel<<<gB, blk, 0, stream>>>(PS, PZ, V, out, 1, 0);
    for (int it = 1; it < 5; ++it) {
      pass_kernel<3><<<gA, blk, 0, stream>>>(Wf, nullptr, nullptr, ut, V, PS, PZ);
      combine_kernel<<<gB, blk, 0, stream>>>(PS, PZ, V, out, 0, it == 4 ? 1 : 0);
    }
  }
}